// Round 2
// baseline (434.641 us; speedup 1.0000x reference)
//
#include <hip/hip_runtime.h>

#define NN   512
#define TT   128
#define DD   128
#define NC   64     // rows per chunk
#define NCHUNK 8
#define SR   132    // hchd row stride (floats): rows 16B-aligned (528B), even bank spread
#define WR   68     // wTt row stride (floats): rows 16B-aligned (272B)

// Precompute per-head projected attention vectors (all fp32):
//   v_h[d] = sum_j W1[d][16h+j]*Wdst[j],  u_h[d] = sum_j W1[d][16h+j]*Wsrc[j]
//   ec[h]  = ba + sum_j b1[16h+j]*(Wsrc[j]+Wdst[j])
// ws layout: [0..1023] vtab[(h>>1)*256 + (d>>2)*8 + (h&1)*4 + (d&3)]
//            [2048..3071] utab[d*8+h] ; [3072..3079] ec[h]
__global__ void gat_prep(const float* __restrict__ W1, const float* __restrict__ b1,
                         const float* __restrict__ Wa, const float* __restrict__ ba,
                         float* __restrict__ ws)
{
  int idx = blockIdx.x*256 + threadIdx.x;   // 0..1023
  int d = idx >> 3, h = idx & 7;
  float v = 0.f, u = 0.f;
  for (int j = 0; j < 16; ++j){
    float w1 = W1[d*DD + h*16 + j];
    v += w1 * Wa[16 + j];
    u += w1 * Wa[j];
  }
  ws[(h>>1)*256 + (d>>2)*8 + (h&1)*4 + (d&3)] = v;
  ws[2048 + d*8 + h] = u;
  if (idx < 8){
    float ec = ba[0];
    for (int j = 0; j < 16; ++j)
      ec += b1[idx*16 + j] * (Wa[j] + Wa[16 + j]);
    ws[3072 + idx] = ec;
  }
}

// One block per (b,t). Flash-style online softmax over 8 chunks of 64 source rows.
// Wave w owns heads {2w, 2w+1}. Score: lane = source row, v-table via SMEM s_loads
// (readfirstlane-uniform pointer). Agg: lane = (dq = l&31, rh = l>>5) accumulates
// BOTH heads over rows 32rh..32rh+31 (full-width 1KB ds_read_b128s). wTt/scale are
// wave-local => no barrier between score and agg. Next chunk register-prefetched.
__global__ __launch_bounds__(256, 4) void gat_main(
    const float* __restrict__ hin, const float* __restrict__ adj, const float* __restrict__ mask,
    const float* __restrict__ W1,  const float* __restrict__ b1,
    const float* __restrict__ W2,  const float* __restrict__ b2,
    const float* __restrict__ ws,  float* __restrict__ out)
{
  __shared__ __align__(16) float hchd[NC*SR];      // 33792 B (epilogue bufs aliased in)
  __shared__ __align__(16) float wTt[8*WR];        // per-head weight rows, 2176 B
  __shared__ float Karr[8], RL[8];
  __shared__ float targ[128];

  // epilogue-only buffers, aliased into hchd (dead after the chunk loop)
  float* const aggfin = hchd;                 // 8*SR = 1056 floats
  float* const catbuf = hchd + 8*SR;          // 256 floats
  float* const oppart = hchd + 8*SR + 256;    // 256 floats

  const int t    = threadIdx.x;
  const int bb   = blockIdx.x >> 7;
  const int tt   = blockIdx.x & 127;
  const int wave = t >> 6;
  const int lane = t & 63;
  const int h0   = 2*wave;

  // wave-uniform pointer into the v-table -> scalar (SMEM) loads, off the DS pipe
  const int wv = __builtin_amdgcn_readfirstlane(wave);
  const float4* __restrict__ vg = (const float4*)(ws + (wv << 8));

  const int dq = lane & 31;   // agg: dim-quad
  const int rh = lane >> 5;   // agg: row-half (0: rows 0-31, 1: rows 32-63)

  float mrun0 = -1e30f, mrun1 = -1e30f;
  float Zp0 = 0.f, Zp1 = 0.f, SWp0 = 0.f, SWp1 = 0.f;   // per-lane partials
  float acc0 = 0.f, acc1 = 0.f, acc2 = 0.f, acc3 = 0.f; // head h0, dims 4dq..+3
  float acc4 = 0.f, acc5 = 0.f, acc6 = 0.f, acc7 = 0.f; // head h0+1

  const float4* __restrict__ hg4 = (const float4*)hin;
  const long dI = 8L*TT*(DD/4);
  const long dC = (long)NC*TT*(DD/4);
  const long g0 = ((long)(bb*NN + (t>>5))*TT + tt)*(DD/4) + (t & 31);
  const int  l0 = (t>>5)*SR + 4*(t & 31);

  float4 pf[8];
  // ---- stage chunk 0 ----
  #pragma unroll
  for (int i = 0; i < 8; ++i) pf[i] = hg4[g0 + (long)i*dI];
  #pragma unroll
  for (int i = 0; i < 8; ++i) *(float4*)&hchd[l0 + i*(8*SR)] = pf[i];
  __syncthreads();

  // row n=0 (contiguous at hchd[0..127]): target_h and score constant K_h
  if (t < 128){
    float a = b1[t];
    for (int d = 0; d < 128; ++d)
      a += hchd[d] * W1[d*DD + t];
    targ[t] = a;
  } else if (t < 136){
    int h8 = t - 128;
    float a = ws[3072 + h8];
    for (int d = 0; d < 128; ++d)
      a += hchd[d] * ws[2048 + d*8 + h8];
    Karr[h8] = a;
  }
  __syncthreads();

  const float K0 = Karr[h0], K1 = Karr[h0 + 1];

  for (int c = 0; c < NCHUNK; ++c){
    // mask/adj for this chunk (issued first so their vmcnt wait doesn't drain pf)
    const int ng = c*NC + lane;
    const float mv = mask[(long)(bb*NN + ng)*TT + tt];
    const float av = adj[(long)(bb*TT + tt)*NN + ng];

    // issue next chunk's global loads; latency hides under score+agg
    if (c < NCHUNK-1){
      const long gc = g0 + (long)(c+1)*dC;
      #pragma unroll
      for (int i = 0; i < 8; ++i) pf[i] = hg4[gc + (long)i*dI];
    }

    // ---- scores: s_h(row=lane) = K_h + h_row . v_h  (v via scalar loads) ----
    float s0 = K0, s1 = K1;
    {
      const float4* rowp = (const float4*)&hchd[lane*SR];
      #pragma unroll 8
      for (int j = 0; j < 32; ++j){
        float4 r4 = rowp[j];
        float4 va = vg[2*j], vb = vg[2*j + 1];
        s0 += r4.x*va.x + r4.y*va.y + r4.z*va.z + r4.w*va.w;
        s1 += r4.x*vb.x + r4.y*vb.y + r4.z*vb.z + r4.w*vb.w;
      }
    }
    const float inva = (av == 0.f) ? 1e-9f : (1.f/av);

    float sm0 = (mv > 0.f) ? s0 : -1e30f;
    float sm1 = (mv > 0.f) ? s1 : -1e30f;
    #pragma unroll
    for (int off = 32; off >= 1; off >>= 1){
      sm0 = fmaxf(sm0, __shfl_xor(sm0, off));
      sm1 = fmaxf(sm1, __shfl_xor(sm1, off));
    }
    float mn0 = fmaxf(mrun0, sm0), mn1 = fmaxf(mrun1, sm1);
    float sc0 = __expf(mrun0 - mn0), sc1 = __expf(mrun1 - mn1);
    mrun0 = mn0; mrun1 = mn1;

    float e0 = (mv > 0.f) ? __expf(s0 - mn0) : 0.f;
    float e1 = (mv > 0.f) ? __expf(s1 - mn1) : 0.f;
    float w0 = e0*inva, w1 = e1*inva;
    wTt[h0*WR + lane]       = w0;
    wTt[(h0 + 1)*WR + lane] = w1;
    Zp0  = Zp0*sc0  + e0;  Zp1  = Zp1*sc1  + e1;   // per-lane partials
    SWp0 = SWp0*sc0 + w0;  SWp1 = SWp1*sc1 + w1;

    // ---- agg (NO barrier: wTt rows h0,h0+1 written by this same wave) ----
    {
      acc0 *= sc0; acc1 *= sc0; acc2 *= sc0; acc3 *= sc0;
      acc4 *= sc1; acc5 *= sc1; acc6 *= sc1; acc7 *= sc1;
      const int rbase = rh*32;
      const float* wr0 = &wTt[h0*WR + rbase];
      const float* wr1 = &wTt[(h0 + 1)*WR + rbase];
      const float* hb  = &hchd[rbase*SR + 4*dq];
      #pragma unroll 4
      for (int g = 0; g < 8; ++g){
        float4 wa = *(const float4*)&wr0[4*g];
        float4 wb = *(const float4*)&wr1[4*g];
        float4 r0 = *(const float4*)&hb[(4*g + 0)*SR];
        float4 r1 = *(const float4*)&hb[(4*g + 1)*SR];
        float4 r2 = *(const float4*)&hb[(4*g + 2)*SR];
        float4 r3 = *(const float4*)&hb[(4*g + 3)*SR];
        acc0 += wa.x*r0.x + wa.y*r1.x + wa.z*r2.x + wa.w*r3.x;
        acc1 += wa.x*r0.y + wa.y*r1.y + wa.z*r2.y + wa.w*r3.y;
        acc2 += wa.x*r0.z + wa.y*r1.z + wa.z*r2.z + wa.w*r3.z;
        acc3 += wa.x*r0.w + wa.y*r1.w + wa.z*r2.w + wa.w*r3.w;
        acc4 += wb.x*r0.x + wb.y*r1.x + wb.z*r2.x + wb.w*r3.x;
        acc5 += wb.x*r0.y + wb.y*r1.y + wb.z*r2.y + wb.w*r3.y;
        acc6 += wb.x*r0.z + wb.y*r1.z + wb.z*r2.z + wb.w*r3.z;
        acc7 += wb.x*r0.w + wb.y*r1.w + wb.z*r2.w + wb.w*r3.w;
      }
    }
    __syncthreads();     // all reads of hchd done
    if (c < NCHUNK-1){
      #pragma unroll
      for (int i = 0; i < 8; ++i) *(float4*)&hchd[l0 + i*(8*SR)] = pf[i];
      __syncthreads();   // tile refilled
    }
  }

  // ---- epilogue ----
  #pragma unroll
  for (int off = 32; off >= 1; off >>= 1){
    Zp0  += __shfl_xor(Zp0,  off);  Zp1  += __shfl_xor(Zp1,  off);
    SWp0 += __shfl_xor(SWp0, off);  SWp1 += __shfl_xor(SWp1, off);
  }
  // combine row-halves: every lane ends with full sums for both heads
  acc0 += __shfl_xor(acc0, 32); acc1 += __shfl_xor(acc1, 32);
  acc2 += __shfl_xor(acc2, 32); acc3 += __shfl_xor(acc3, 32);
  acc4 += __shfl_xor(acc4, 32); acc5 += __shfl_xor(acc5, 32);
  acc6 += __shfl_xor(acc6, 32); acc7 += __shfl_xor(acc7, 32);

  if (lane == 0){
    RL[h0]     = SWp0 / Zp0;
    RL[h0 + 1] = SWp1 / Zp1;
  }
  {
    float invZ = (rh == 0) ? (1.f/Zp0) : (1.f/Zp1);
    float4 o;
    o.x = ((rh == 0) ? acc0 : acc4) * invZ;
    o.y = ((rh == 0) ? acc1 : acc5) * invZ;
    o.z = ((rh == 0) ? acc2 : acc6) * invZ;
    o.w = ((rh == 0) ? acc3 : acc7) * invZ;
    *(float4*)&aggfin[(h0 + rh)*SR + 4*dq] = o;
  }
  __syncthreads();

  // cat[0:128] = project weighted sum through W1 head-slice; cat[128:256] = target_h
  if (t < 128){
    int h2 = t >> 4;
    float a = RL[h2] * b1[t];
    for (int d = 0; d < 128; ++d)
      a += aggfin[h2*SR + d] * W1[d*DD + t];
    catbuf[t]       = a;
    catbuf[128 + t] = targ[t];
  }
  __syncthreads();

  // out = cat @ W2 + b2 (2-way k-split)
  {
    int j = t & 127, kh = t >> 7;
    float o = 0.f;
    for (int k = kh*128; k < kh*128 + 128; ++k)
      o += catbuf[k] * W2[k*DD + j];
    oppart[t] = o;
  }
  __syncthreads();
  if (t < 128)
    out[(long)blockIdx.x*128 + t] = oppart[t] + oppart[128 + t] + b2[t];
}

extern "C" void kernel_launch(void* const* d_in, const int* in_sizes, int n_in,
                              void* d_out, int out_size, void* d_ws, size_t ws_size,
                              hipStream_t stream) {
  const float* h    = (const float*)d_in[0];
  const float* adj  = (const float*)d_in[1];
  const float* mask = (const float*)d_in[2];
  const float* W1   = (const float*)d_in[3];
  const float* b1   = (const float*)d_in[4];
  const float* Wa   = (const float*)d_in[5];
  const float* ba   = (const float*)d_in[6];
  const float* W2   = (const float*)d_in[7];
  const float* b2   = (const float*)d_in[8];
  float* ws  = (float*)d_ws;
  float* out = (float*)d_out;

  gat_prep<<<4, 256, 0, stream>>>(W1, b1, Wa, ba, ws);
  gat_main<<<1024, 256, 0, stream>>>(h, adj, mask, W1, b1, W2, b2, ws, out);
}

// Round 4
// 411.488 us; speedup vs baseline: 1.0563x; 1.0563x over previous
//
#include <hip/hip_runtime.h>

#define NN   512
#define TT   128
#define DD   128
#define NC   64     // rows per chunk
#define NCHUNK 8
#define SR   132    // hchd row stride (floats): rows 16B-aligned (528B), even bank spread
#define WR   68     // wTt row stride (floats): rows 16B-aligned (272B)

// Precompute per-head projected attention vectors (all fp32):
//   v_h[d] = sum_j W1[d][16h+j]*Wdst[j],  u_h[d] = sum_j W1[d][16h+j]*Wsrc[j]
//   ec[h]  = ba + sum_j b1[16h+j]*(Wsrc[j]+Wdst[j])
// ws layout: [0..1023] vtab[(h>>1)*256 + (d>>2)*8 + (h&1)*4 + (d&3)]
//            [2048..3071] utab[d*8+h] ; [3072..3079] ec[h]
__global__ void gat_prep(const float* __restrict__ W1, const float* __restrict__ b1,
                         const float* __restrict__ Wa, const float* __restrict__ ba,
                         float* __restrict__ ws)
{
  int idx = blockIdx.x*256 + threadIdx.x;   // 0..1023
  int d = idx >> 3, h = idx & 7;
  float v = 0.f, u = 0.f;
  for (int j = 0; j < 16; ++j){
    float w1 = W1[d*DD + h*16 + j];
    v += w1 * Wa[16 + j];
    u += w1 * Wa[j];
  }
  ws[(h>>1)*256 + (d>>2)*8 + (h&1)*4 + (d&3)] = v;
  ws[2048 + d*8 + h] = u;
  if (idx < 8){
    float ec = ba[0];
    for (int j = 0; j < 16; ++j)
      ec += b1[idx*16 + j] * (Wa[j] + Wa[16 + j]);
    ws[3072 + idx] = ec;
  }
}

// One block per (b,t). Flash-style online softmax over 8 chunks of 64 source rows.
// Wave w owns heads {2w, 2w+1}. Score: lane = source row, v-table via SMEM s_loads
// (readfirstlane-uniform pointer). Agg: lane = (dq = l&31, rh = l>>5) accumulates
// BOTH heads over rows 32rh..32rh+31 (full-width 1KB ds_read_b128s). wTt/scale are
// wave-local => no barrier between score and agg. Next chunk prefetched into 8
// NAMED float4 registers (array form spilled to scratch: R2 showed 251MB WRITE_SIZE).
__global__ __launch_bounds__(256, 4) void gat_main(
    const float* __restrict__ hin, const float* __restrict__ adj, const float* __restrict__ mask,
    const float* __restrict__ W1,  const float* __restrict__ b1,
    const float* __restrict__ W2,  const float* __restrict__ b2,
    const float* __restrict__ ws,  float* __restrict__ out)
{
  __shared__ __align__(16) float hchd[NC*SR];      // 33792 B (epilogue bufs aliased in)
  __shared__ __align__(16) float wTt[8*WR];        // per-head weight rows, 2176 B
  __shared__ float Karr[8], RL[8];
  __shared__ float targ[128];

  // epilogue-only buffers, aliased into hchd (dead after the chunk loop)
  float* const aggfin = hchd;                 // 8*SR = 1056 floats
  float* const catbuf = hchd + 8*SR;          // 256 floats
  float* const oppart = hchd + 8*SR + 256;    // 256 floats

  const int t    = threadIdx.x;
  const int bb   = blockIdx.x >> 7;
  const int tt   = blockIdx.x & 127;
  const int wave = t >> 6;
  const int lane = t & 63;
  const int h0   = 2*wave;

  // wave-uniform pointer into the v-table -> scalar (SMEM) loads, off the DS pipe
  const int wv = __builtin_amdgcn_readfirstlane(wave);
  const float4* __restrict__ vg = (const float4*)(ws + (wv << 8));

  const int dq = lane & 31;   // agg: dim-quad
  const int rh = lane >> 5;   // agg: row-half (0: rows 0-31, 1: rows 32-63)

  float mrun0 = -1e30f, mrun1 = -1e30f;
  float Zp0 = 0.f, Zp1 = 0.f, SWp0 = 0.f, SWp1 = 0.f;   // per-lane partials
  float acc0 = 0.f, acc1 = 0.f, acc2 = 0.f, acc3 = 0.f; // head h0, dims 4dq..+3
  float acc4 = 0.f, acc5 = 0.f, acc6 = 0.f, acc7 = 0.f; // head h0+1

  const float4* __restrict__ hg4 = (const float4*)hin;
  const long dI = 8L*TT*(DD/4);
  const long dC = (long)NC*TT*(DD/4);
  const long g0 = ((long)(bb*NN + (t>>5))*TT + tt)*(DD/4) + (t & 31);
  const int  l0 = (t>>5)*SR + 4*(t & 31);

  // prefetch registers: 8 NAMED float4 (never an array => never scratch)
  float4 pf0, pf1, pf2, pf3, pf4, pf5, pf6, pf7;

#define PF_LOAD(GC) do{ const long _g = (GC); \
    pf0 = hg4[_g];        pf1 = hg4[_g + dI];   pf2 = hg4[_g + 2*dI]; pf3 = hg4[_g + 3*dI]; \
    pf4 = hg4[_g + 4*dI]; pf5 = hg4[_g + 5*dI]; pf6 = hg4[_g + 6*dI]; pf7 = hg4[_g + 7*dI]; }while(0)
#define PF_STORE() do{ \
    *(float4*)&hchd[l0 + 0*(8*SR)] = pf0; *(float4*)&hchd[l0 + 1*(8*SR)] = pf1; \
    *(float4*)&hchd[l0 + 2*(8*SR)] = pf2; *(float4*)&hchd[l0 + 3*(8*SR)] = pf3; \
    *(float4*)&hchd[l0 + 4*(8*SR)] = pf4; *(float4*)&hchd[l0 + 5*(8*SR)] = pf5; \
    *(float4*)&hchd[l0 + 6*(8*SR)] = pf6; *(float4*)&hchd[l0 + 7*(8*SR)] = pf7; }while(0)

  // ---- stage chunk 0 ----
  PF_LOAD(g0);
  PF_STORE();
  __syncthreads();

  // row n=0 (contiguous at hchd[0..127]): target_h and score constant K_h
  if (t < 128){
    float a = b1[t];
    for (int d = 0; d < 128; ++d)
      a += hchd[d] * W1[d*DD + t];
    targ[t] = a;
  } else if (t < 136){
    int h8 = t - 128;
    float a = ws[3072 + h8];
    for (int d = 0; d < 128; ++d)
      a += hchd[d] * ws[2048 + d*8 + h8];
    Karr[h8] = a;
  }
  __syncthreads();

  const float K0 = Karr[h0], K1 = Karr[h0 + 1];

  for (int c = 0; c < NCHUNK; ++c){
    // mask/adj for this chunk (issued first so their vmcnt wait doesn't drain pf)
    const int ng = c*NC + lane;
    const float mv = mask[(long)(bb*NN + ng)*TT + tt];
    const float av = adj[(long)(bb*TT + tt)*NN + ng];

    // issue next chunk's global loads; latency hides under score+agg
    if (c < NCHUNK-1){
      PF_LOAD(g0 + (long)(c+1)*dC);
    }

    // ---- scores: s_h(row=lane) = K_h + h_row . v_h  (v via scalar loads) ----
    float s0 = K0, s1 = K1;
    {
      const float4* rowp = (const float4*)&hchd[lane*SR];
      #pragma unroll 8
      for (int j = 0; j < 32; ++j){
        float4 r4 = rowp[j];
        float4 va = vg[2*j], vb = vg[2*j + 1];
        s0 += r4.x*va.x + r4.y*va.y + r4.z*va.z + r4.w*va.w;
        s1 += r4.x*vb.x + r4.y*vb.y + r4.z*vb.z + r4.w*vb.w;
      }
    }
    const float inva = (av == 0.f) ? 1e-9f : (1.f/av);

    float sm0 = (mv > 0.f) ? s0 : -1e30f;
    float sm1 = (mv > 0.f) ? s1 : -1e30f;
    #pragma unroll
    for (int off = 32; off >= 1; off >>= 1){
      sm0 = fmaxf(sm0, __shfl_xor(sm0, off));
      sm1 = fmaxf(sm1, __shfl_xor(sm1, off));
    }
    float mn0 = fmaxf(mrun0, sm0), mn1 = fmaxf(mrun1, sm1);
    float sc0 = __expf(mrun0 - mn0), sc1 = __expf(mrun1 - mn1);
    mrun0 = mn0; mrun1 = mn1;

    float e0 = (mv > 0.f) ? __expf(s0 - mn0) : 0.f;
    float e1 = (mv > 0.f) ? __expf(s1 - mn1) : 0.f;
    float w0 = e0*inva, w1 = e1*inva;
    wTt[h0*WR + lane]       = w0;
    wTt[(h0 + 1)*WR + lane] = w1;
    Zp0  = Zp0*sc0  + e0;  Zp1  = Zp1*sc1  + e1;   // per-lane partials
    SWp0 = SWp0*sc0 + w0;  SWp1 = SWp1*sc1 + w1;

    // ---- agg (NO barrier: wTt rows h0,h0+1 written by this same wave) ----
    {
      acc0 *= sc0; acc1 *= sc0; acc2 *= sc0; acc3 *= sc0;
      acc4 *= sc1; acc5 *= sc1; acc6 *= sc1; acc7 *= sc1;
      const int rbase = rh*32;
      const float* wr0 = &wTt[h0*WR + rbase];
      const float* wr1 = &wTt[(h0 + 1)*WR + rbase];
      const float* hb  = &hchd[rbase*SR + 4*dq];
      #pragma unroll 4
      for (int g = 0; g < 8; ++g){
        float4 wa = *(const float4*)&wr0[4*g];
        float4 wb = *(const float4*)&wr1[4*g];
        float4 r0 = *(const float4*)&hb[(4*g + 0)*SR];
        float4 r1 = *(const float4*)&hb[(4*g + 1)*SR];
        float4 r2 = *(const float4*)&hb[(4*g + 2)*SR];
        float4 r3 = *(const float4*)&hb[(4*g + 3)*SR];
        acc0 += wa.x*r0.x + wa.y*r1.x + wa.z*r2.x + wa.w*r3.x;
        acc1 += wa.x*r0.y + wa.y*r1.y + wa.z*r2.y + wa.w*r3.y;
        acc2 += wa.x*r0.z + wa.y*r1.z + wa.z*r2.z + wa.w*r3.z;
        acc3 += wa.x*r0.w + wa.y*r1.w + wa.z*r2.w + wa.w*r3.w;
        acc4 += wb.x*r0.x + wb.y*r1.x + wb.z*r2.x + wb.w*r3.x;
        acc5 += wb.x*r0.y + wb.y*r1.y + wb.z*r2.y + wb.w*r3.y;
        acc6 += wb.x*r0.z + wb.y*r1.z + wb.z*r2.z + wb.w*r3.z;
        acc7 += wb.x*r0.w + wb.y*r1.w + wb.z*r2.w + wb.w*r3.w;
      }
    }
    __syncthreads();     // all reads of hchd done
    if (c < NCHUNK-1){
      PF_STORE();
      __syncthreads();   // tile refilled
    }
  }

  // ---- epilogue ----
  #pragma unroll
  for (int off = 32; off >= 1; off >>= 1){
    Zp0  += __shfl_xor(Zp0,  off);  Zp1  += __shfl_xor(Zp1,  off);
    SWp0 += __shfl_xor(SWp0, off);  SWp1 += __shfl_xor(SWp1, off);
  }
  // combine row-halves: every lane ends with full sums for both heads
  acc0 += __shfl_xor(acc0, 32); acc1 += __shfl_xor(acc1, 32);
  acc2 += __shfl_xor(acc2, 32); acc3 += __shfl_xor(acc3, 32);
  acc4 += __shfl_xor(acc4, 32); acc5 += __shfl_xor(acc5, 32);
  acc6 += __shfl_xor(acc6, 32); acc7 += __shfl_xor(acc7, 32);

  if (lane == 0){
    RL[h0]     = SWp0 / Zp0;
    RL[h0 + 1] = SWp1 / Zp1;
  }
  {
    float invZ = (rh == 0) ? (1.f/Zp0) : (1.f/Zp1);
    float4 o;
    o.x = ((rh == 0) ? acc0 : acc4) * invZ;
    o.y = ((rh == 0) ? acc1 : acc5) * invZ;
    o.z = ((rh == 0) ? acc2 : acc6) * invZ;
    o.w = ((rh == 0) ? acc3 : acc7) * invZ;
    *(float4*)&aggfin[(h0 + rh)*SR + 4*dq] = o;
  }
  __syncthreads();

  // cat[0:128] = project weighted sum through W1 head-slice; cat[128:256] = target_h
  if (t < 128){
    int h2 = t >> 4;
    float a = RL[h2] * b1[t];
    for (int d = 0; d < 128; ++d)
      a += aggfin[h2*SR + d] * W1[d*DD + t];
    catbuf[t]       = a;
    catbuf[128 + t] = targ[t];
  }
  __syncthreads();

  // out = cat @ W2 + b2 (2-way k-split)
  {
    int j = t & 127, kh = t >> 7;
    float o = 0.f;
    for (int k = kh*128; k < kh*128 + 128; ++k)
      o += catbuf[k] * W2[k*DD + j];
    oppart[t] = o;
  }
  __syncthreads();
  if (t < 128)
    out[(long)blockIdx.x*128 + t] = oppart[t] + oppart[128 + t] + b2[t];
}

extern "C" void kernel_launch(void* const* d_in, const int* in_sizes, int n_in,
                              void* d_out, int out_size, void* d_ws, size_t ws_size,
                              hipStream_t stream) {
  const float* h    = (const float*)d_in[0];
  const float* adj  = (const float*)d_in[1];
  const float* mask = (const float*)d_in[2];
  const float* W1   = (const float*)d_in[3];
  const float* b1   = (const float*)d_in[4];
  const float* Wa   = (const float*)d_in[5];
  const float* ba   = (const float*)d_in[6];
  const float* W2   = (const float*)d_in[7];
  const float* b2   = (const float*)d_in[8];
  float* ws  = (float*)d_ws;
  float* out = (float*)d_out;

  gat_prep<<<4, 256, 0, stream>>>(W1, b1, Wa, ba, ws);
  gat_main<<<1024, 256, 0, stream>>>(h, adj, mask, W1, b1, W2, b2, ws, out);
}